// Round 6
// baseline (134.629 us; speedup 1.0000x reference)
//
#include <hip/hip_runtime.h>

#define BATCH 32
#define H 512
#define W 512
#define PADR 4
#define WIN 9
#define SEG 16                      // output rows per block
#define COLS 8                      // output columns per thread (lane)
#define NT 64                       // ONE wave per block: 64 x 8 = 512 cols
#define NSTEP (SEG + WIN - 1)       // 24 row-steps, fully unrolled
// final scalar = sum over pixels of ((1-cc1)+(1-cc2)) * 0.5 / (B*H*W)
#define SCALE (0.5f / 8388608.0f)

typedef float v4f __attribute__((ext_vector_type(4)));

// Round 6: kill the phase-lock.
// R2-R5 evidence: dur invariant to waves/CU (8 vs 16) and to LDS/VALU volume;
// LDS-pipe time + VALU time + VMEM time ~= dur  =>  pipes run in SUM, not MAX:
// the write->barrier->read emit structure phase-locks every wave on the CU.
// Fix: one wave spans the whole row; horizontal exchange via DPP wave shifts
// (in-register, VALU pipe, no LDS, no barriers anywhere).  bound_ctrl=1 makes
// lanes 0/63 receive 0 = exact conv zero-padding at image edges.

__device__ __forceinline__ float from_left(float v) {   // lane i <- lane i-1; lane 0 <- 0
    return __builtin_bit_cast(float, __builtin_amdgcn_update_dpp(
        0, __builtin_bit_cast(int, v), 0x138, 0xF, 0xF, true)); // wave_shr:1
}
__device__ __forceinline__ float from_right(float v) {  // lane i <- lane i+1; lane 63 <- 0
    return __builtin_bit_cast(float, __builtin_amdgcn_update_dpp(
        0, __builtin_bit_cast(int, v), 0x130, 0xF, 0xF, true)); // wave_shl:1
}

// Horizontal 9-window sums for this lane's 8 columns of quantity qi.
// Own-tile prefixes p1..p7,T; left lane supplies suffixes (T-p4..T-p7),
// right lane supplies prefixes (p1..p4).  8 DPP + ~21 VALU per quantity.
#define EMITQ(qi) do {                                        \
    const float p1 = V[qi][0];                                \
    const float p2 = p1 + V[qi][1];                           \
    const float p3 = p2 + V[qi][2];                           \
    const float p4 = p3 + V[qi][3];                           \
    const float p5 = p4 + V[qi][4];                           \
    const float p6 = p5 + V[qi][5];                           \
    const float p7 = p6 + V[qi][6];                           \
    const float T  = p7 + V[qi][7];                           \
    const float l0 = from_left(T - p4);                       \
    const float l1 = from_left(T - p5);                       \
    const float l2 = from_left(T - p6);                       \
    const float l3 = from_left(V[qi][7]);  /* T - p7 */       \
    const float r4 = from_right(p1);                          \
    const float r5 = from_right(p2);                          \
    const float r6 = from_right(p3);                          \
    const float r7 = from_right(p4);                          \
    S[qi][0] = l0 + p5;                                       \
    S[qi][1] = l1 + p6;                                       \
    S[qi][2] = l2 + p7;                                       \
    S[qi][3] = l3 + T;                                        \
    S[qi][4] = T + r4;                                        \
    S[qi][5] = (T - p1) + r5;                                 \
    S[qi][6] = (T - p2) + r6;                                 \
    S[qi][7] = (T - p3) + r7;                                 \
} while (0)

__global__ __launch_bounds__(NT, 1) void ncc_loss_kernel(
    const float* __restrict__ g1, const float* __restrict__ g2,
    const float* __restrict__ gf, float* __restrict__ out)
{
    const int t  = threadIdx.x;              // 0..63 (one wave)
    const int x0 = t * COLS;                 // 0,8,...,504
    const int y0 = blockIdx.y * SEG;
    const int b  = blockIdx.z;
    const size_t base = (size_t)b * (size_t)(H * W);
    const int voff = x0 * 4;                 // in-bounds: 2016+16+16 <= 2048

    // Double-buffered prefetch: [parity][image][half], 2 x v4f = 8 px.
    v4f buf[2][3][2];
    auto load_row = [&](int step, int par) {
        const int yr  = y0 - PADR + step;
        const int rec = ((unsigned)yr < (unsigned)H) ? (W * 4) : 0; // OOB row -> 0
        const int yc  = yr < 0 ? 0 : (yr >= H ? H - 1 : yr);        // safe base
        const size_t roff = base + (size_t)yc * W;                  // block-uniform
        __amdgpu_buffer_rsrc_t r1 = __builtin_amdgcn_make_buffer_rsrc(
            (void*)(g1 + roff), (short)0, rec, 0x00020000);
        __amdgpu_buffer_rsrc_t r2 = __builtin_amdgcn_make_buffer_rsrc(
            (void*)(g2 + roff), (short)0, rec, 0x00020000);
        __amdgpu_buffer_rsrc_t rf = __builtin_amdgcn_make_buffer_rsrc(
            (void*)(gf + roff), (short)0, rec, 0x00020000);
        buf[par][0][0] = __builtin_bit_cast(v4f,
            __builtin_amdgcn_raw_buffer_load_b128(r1, voff, 0, 0));
        buf[par][0][1] = __builtin_bit_cast(v4f,
            __builtin_amdgcn_raw_buffer_load_b128(r1, voff + 16, 0, 0));
        buf[par][1][0] = __builtin_bit_cast(v4f,
            __builtin_amdgcn_raw_buffer_load_b128(r2, voff, 0, 0));
        buf[par][1][1] = __builtin_bit_cast(v4f,
            __builtin_amdgcn_raw_buffer_load_b128(r2, voff + 16, 0, 0));
        buf[par][2][0] = __builtin_bit_cast(v4f,
            __builtin_amdgcn_raw_buffer_load_b128(rf, voff, 0, 0));
        buf[par][2][1] = __builtin_bit_cast(v4f,
            __builtin_amdgcn_raw_buffer_load_b128(rf, voff + 16, 0, 0));
    };

    // Raw-pixel vertical ring (compile-time indices after full unroll).
    float ring[3][WIN][COLS];
#pragma unroll
    for (int im = 0; im < 3; ++im)
#pragma unroll
        for (int i = 0; i < WIN; ++i)
#pragma unroll
            for (int c = 0; c < COLS; ++c) ring[im][i][c] = 0.f;

    // Vertical running box-sums: q = {A, C, F, AA, CC, FF, AF, CF}.
    float V[8][COLS];
#pragma unroll
    for (int q = 0; q < 8; ++q)
#pragma unroll
        for (int c = 0; c < COLS; ++c) V[q][c] = 0.f;

    float lsum = 0.f;
    const float inv_n = 1.0f / 81.0f;

    load_row(0, 0);                          // prologue prefetch

#pragma unroll
    for (int s = 0; s < NSTEP; ++s) {
        if (s + 1 < NSTEP) load_row(s + 1, (s + 1) & 1);   // compile-time guard

        const int ph = s % WIN;              // compile-time

        // vertical sliding update: V += new - old (products folded as fma)
#pragma unroll
        for (int c = 0; c < COLS; ++c) {
            const float n1 = buf[s & 1][0][c >> 2][c & 3];
            const float n2 = buf[s & 1][1][c >> 2][c & 3];
            const float nf = buf[s & 1][2][c >> 2][c & 3];
            const float o1 = ring[0][ph][c], o2 = ring[1][ph][c],
                        of = ring[2][ph][c];
            V[0][c] += n1 - o1;
            V[1][c] += n2 - o2;
            V[2][c] += nf - of;
            V[3][c] = fmaf(n1, n1, fmaf(-o1, o1, V[3][c]));
            V[4][c] = fmaf(n2, n2, fmaf(-o2, o2, V[4][c]));
            V[5][c] = fmaf(nf, nf, fmaf(-of, of, V[5][c]));
            V[6][c] = fmaf(n1, nf, fmaf(-o1, of, V[6][c]));
            V[7][c] = fmaf(n2, nf, fmaf(-o2, of, V[7][c]));
            ring[0][ph][c] = n1; ring[1][ph][c] = n2; ring[2][ph][c] = nf;
        }

        if (s >= WIN - 1) {                  // emit output row y0 + s - 8
            float S[8][COLS];
            EMITQ(0); EMITQ(1); EMITQ(2); EMITQ(3);
            EMITQ(4); EMITQ(5); EMITQ(6); EMITQ(7);

            // NCC epilogue per column
#pragma unroll
            for (int c = 0; c < COLS; ++c) {
                const float sA = S[0][c], sC = S[1][c], sF = S[2][c];
                const float u1 = sA * inv_n;
                const float u2 = sC * inv_n;
                const float uf = sF * inv_n;
                const float cross1 = fmaf(-sA, uf, S[6][c]);
                const float var1   = fmaf(-sA, u1, S[3][c]);
                const float varf   = fmaf(-sF, uf, S[5][c]);
                const float cross2 = fmaf(-sC, uf, S[7][c]);
                const float var2   = fmaf(-sC, u2, S[4][c]);
                const float d1 = fmaf(var1, varf, 1e-5f);
                const float d2 = fmaf(var2, varf, 1e-5f);
                // cc1 + cc2 = (cross1^2*d2 + cross2^2*d1)/(d1*d2): single rcp
                const float inv = __builtin_amdgcn_rcpf(d1 * d2);
                float num = cross1 * cross1 * d2;
                num = fmaf(cross2 * cross2, d1, num);
                lsum += fmaf(-num, inv, 2.0f);   // (1-cc1)+(1-cc2)
            }
        }
    }

    // single-wave reduction: shuffle only, one atomic per block, no LDS
#pragma unroll
    for (int offd = 32; offd > 0; offd >>= 1)
        lsum += __shfl_down(lsum, offd);
    if (t == 0) atomicAdd(out, lsum * SCALE);
}

extern "C" void kernel_launch(void* const* d_in, const int* in_sizes, int n_in,
                              void* d_out, int out_size, void* d_ws, size_t ws_size,
                              hipStream_t stream) {
    const float* img1 = (const float*)d_in[0];
    const float* img2 = (const float*)d_in[1];
    const float* fimg = (const float*)d_in[2];
    float* out = (float*)d_out;

    hipMemsetAsync(out, 0, sizeof(float), stream);  // d_out re-poisoned each call

    dim3 grid(1, H / SEG, BATCH);        // (1, 32, 32) = 1024 blocks, 1 wave each
    ncc_loss_kernel<<<grid, dim3(NT), 0, stream>>>(img1, img2, fimg, out);
}